// Round 12
// baseline (731.288 us; speedup 1.0000x reference)
//
#include <hip/hip_runtime.h>
#include <hip/hip_bf16.h>
#include <stdint.h>

#define M_DIM 16384   // B*T = 4*4096
#define K_DIM 2048    // H
#define N_DIM 6144    // 3H
#define NT    32      // K-tiles per output tile (K_DIM/64)
#define NTILES 6      // output tiles per persistent block (1536/256)

typedef __attribute__((ext_vector_type(8))) short bf16x8;
typedef __attribute__((ext_vector_type(8))) unsigned short u16x8;
typedef __attribute__((ext_vector_type(4))) float f32x4;

__device__ __forceinline__ unsigned short f2bf(float f) {
  unsigned int u = __float_as_uint(f);
  u += 0x7FFFu + ((u >> 16) & 1u);   // RNE
  return (unsigned short)(u >> 16);
}

__device__ __forceinline__ void load_lds16(const void* g, void* l) {
  __builtin_amdgcn_global_load_lds((const __attribute__((address_space(1))) void*)g,
                                   (__attribute__((address_space(3))) void*)l, 16, 0, 0);
}

#define FENCE asm volatile("" ::: "memory")
#define BAR   do { FENCE; __builtin_amdgcn_s_barrier(); FENCE; } while (0)

// ---------- Pass 1: fused input conversion ----------
// blocks [0,2048): hidden fp32 -> bf16 straight copy (NT loads).
// blocks [2048,5120): w_qkv [K][N] -> Wt [N][K] bf16 transpose via LDS.
__global__ __launch_bounds__(256) void cvt_fused(const float* __restrict__ hidden,
                                                 unsigned short* __restrict__ outh,
                                                 const float* __restrict__ w,
                                                 unsigned short* __restrict__ wt) {
  __shared__ float tile[64][69];
  const int bid = blockIdx.x;
  const int t = threadIdx.x;
  if (bid < 2048) {
    unsigned int base = bid * 256u + t;
    #pragma unroll
    for (int i = 0; i < 16; ++i) {
      unsigned int fi = i * 524288u + base;
      f32x4 v = __builtin_nontemporal_load(reinterpret_cast<const f32x4*>(hidden) + fi);
      ushort4 o;
      o.x = f2bf(v[0]); o.y = f2bf(v[1]); o.z = f2bf(v[2]); o.w = f2bf(v[3]);
      reinterpret_cast<ushort4*>(outh)[fi] = o;
    }
  } else {
    const int wb = bid - 2048;                  // 0..3071
    const int k0 = (wb / 96) * 64;              // 32 k-tiles
    const int n0 = (wb % 96) * 64;              // 96 n-tiles
    #pragma unroll
    for (int i = 0; i < 4; ++i) {
      int idx = i * 256 + t;
      int row = idx >> 4, c4 = idx & 15;
      f32x4 v = __builtin_nontemporal_load(reinterpret_cast<const f32x4*>(
          &w[(size_t)(k0 + row) * N_DIM + n0 + c4 * 4]));
      tile[row][c4 * 4 + 0] = v[0]; tile[row][c4 * 4 + 1] = v[1];
      tile[row][c4 * 4 + 2] = v[2]; tile[row][c4 * 4 + 3] = v[3];
    }
    __syncthreads();
    #pragma unroll
    for (int i = 0; i < 2; ++i) {
      int idx = i * 256 + t;
      int n = idx >> 3, k8 = idx & 7;
      u16x8 v;
      #pragma unroll
      for (int e = 0; e < 8; ++e) v[e] = f2bf(tile[k8 * 8 + e][n]);
      *reinterpret_cast<u16x8*>(&wt[(size_t)(n0 + n) * K_DIM + k0 + k8 * 8]) = v;
    }
  }
}

// ---------- Pass 2: persistent seamless 256x256x64 8-phase bf16 MFMA GEMM ----
// R12 = R11 + de-branched steady loop + exact counted waits:
//   - staging pointers are running per-thread pointers (sA += 64 elems/iter);
//     one wave-uniform wrap (sA=gAn) at t==NT-3 replaces per-iter ternaries.
//   - steady wait vmcnt(8): FIFO invariant "8 left in flight = K(t+2) whole";
//     retires exactly K(t+1). Boundary t==0 (j>0): vmcnt(40) (32 stores +
//     K(t+2) younger); no-stage tail: vmcnt(0).
//   - ph1 reads b0 before a: first MFMA's operands land first under the
//     compiler's fine-grained lgkmcnt scheduling (R11 evidence).
// Rest identical to R11: no manual lgkm drains; stage spreading ph2 A{0,2} /
//   ph3 B{0,1} / ph4 B{2,3}+A{1,3}; stores through L2; bias in LDS;
//   swapped-operand MFMA -> f32x4 stores.
__global__ __launch_bounds__(512, 2) void gemm_qkv_8ph(const unsigned short* __restrict__ A,
                                                       const unsigned short* __restrict__ Bt,
                                                       const float* __restrict__ bias,
                                                       float* __restrict__ out) {
  extern __shared__ __align__(16) char smem[];
  const int tid = threadIdx.x, lane = tid & 63, wid = tid >> 6;
  const int wm = wid >> 2, wn = wid & 3;        // 2 x 4 wave grid, 128x64 per wave

  const int xcd = blockIdx.x & 7;
  const int lcl = blockIdx.x >> 3;              // 0..31 within XCD

  const int srow  = tid >> 3;
  const int sslot = (tid & 7) ^ ((tid >> 3) & 7);
  const int r15 = lane & 15, q4 = lane >> 4, x7 = lane & 7;
  const int abase = (wm * 128 + r15) * 128;
  const int bbase = (wn * 64  + r15) * 128;
  const int sw0 = ((0 + q4) ^ x7) * 16;
  const int sw1 = ((4 + q4) ^ x7) * 16;

  // full-tile stage (prologue only): 4 x gload_lds(16B)/thread
  #define STAGE_T(gsrc, ldsbase)                                              \
    { const unsigned short* _g = (gsrc); char* _l = (ldsbase);                \
      load_lds16(_g,                       _l +     wid * 1024);              \
      load_lds16(_g + (size_t)64  * K_DIM, _l + 8192  + wid * 1024);          \
      load_lds16(_g + (size_t)128 * K_DIM, _l + 16384 + wid * 1024);          \
      load_lds16(_g + (size_t)192 * K_DIM, _l + 24576 + wid * 1024); }

  // half-tile stage: chunks cA,cB (each chunk = 64 rows = 8KB)
  #define STAGE_H2(gsrc, ldsbase, cA, cB)                                     \
    { const unsigned short* _g = (gsrc); char* _l = (ldsbase);                \
      load_lds16(_g + (size_t)((cA) * 64) * K_DIM, _l + (cA) * 8192 + wid * 1024); \
      load_lds16(_g + (size_t)((cB) * 64) * K_DIM, _l + (cB) * 8192 + wid * 1024); }

  #define TILE_MAP(jj, m0_, n0_, gA_, gB_)                                    \
    { const int bm_ = xcd * 8 + (lcl >> 2);                                   \
      const int bn_ = (jj) * 4 + (lcl & 3);                                   \
      m0_ = bm_ * 256; n0_ = bn_ * 256;                                       \
      gA_ = A  + (size_t)(m0_ + srow) * K_DIM + sslot * 8;                    \
      gB_ = Bt + (size_t)(n0_ + srow) * K_DIM + sslot * 8; }

  // ---- bias preload into LDS corner (once): 6 tiles x 256 floats ----
  if (tid < 384) {
    const int jj = tid / 64;
    const int o  = (tid & 63) * 4;
    const int bn_ = jj * 4 + (lcl & 3);
    f32x4 bv = *reinterpret_cast<const f32x4*>(&bias[bn_ * 256 + o]);
    *reinterpret_cast<f32x4*>(smem + 131072 + jj * 1024 + o * 4) = bv;
  }

  // ---- first-tile prologue: K0 + K1 (16 loads), vmcnt(8) => K0 landed ----
  int m0, n0, m0n, n0n;
  const unsigned short *gA, *gB, *gAn, *gBn;
  TILE_MAP(0, m0, n0, gA, gB);
  {
    char* A0 = smem;          char* B0 = smem + 32768;
    char* A1 = smem + 65536;  char* B1 = smem + 98304;
    STAGE_T(gB +  0, B0); STAGE_T(gA +  0, A0);
    STAGE_T(gB + 64, B1); STAGE_T(gA + 64, A1);
    asm volatile("s_waitcnt vmcnt(8)" ::: "memory");
    BAR;
  }

  for (int j = 0; j < NTILES; ++j) {
    const int jn = (j + 1 < NTILES) ? j + 1 : j;
    TILE_MAP(jn, m0n, n0n, gAn, gBn);

    f32x4 acc[2][2][4][2] = {};                        // [qm][qn][mi][ni]
    bf16x8 a[4][2], b0[2][2], b1[2][2];

    // running staging pointers: at iter t they source K(t+2)
    const unsigned short* sA = gA + 128;               // 2*64 elems
    const unsigned short* sB = gB + 128;
    char* Ab = smem;                                   // K(t)'s buffer

    for (int t = 0; t < NT; ++t) {
      char* Bb = Ab + 32768;
      const bool st = (t + 2 < NT) || (j + 1 < NTILES);

      // ---- ph1: read B(qn0) then A(qm0); MFMA quad(0,0) ----
      #pragma unroll
      for (int ni = 0; ni < 2; ++ni) {
        const char* p = Bb + bbase + ni * (16 * 128);
        b0[ni][0] = *(const bf16x8*)(p + sw0);
        b0[ni][1] = *(const bf16x8*)(p + sw1);
      }
      #pragma unroll
      for (int mi = 0; mi < 4; ++mi) {
        const char* p = Ab + abase + mi * (16 * 128);
        a[mi][0] = *(const bf16x8*)(p + sw0);
        a[mi][1] = *(const bf16x8*)(p + sw1);
      }
      BAR;
      __builtin_amdgcn_s_setprio(1);
      #pragma unroll
      for (int mi = 0; mi < 4; ++mi)
        #pragma unroll
        for (int ni = 0; ni < 2; ++ni) {
          acc[0][0][mi][ni] = __builtin_amdgcn_mfma_f32_16x16x32_bf16(b0[ni][0], a[mi][0], acc[0][0][mi][ni], 0, 0, 0);
          acc[0][0][mi][ni] = __builtin_amdgcn_mfma_f32_16x16x32_bf16(b0[ni][1], a[mi][1], acc[0][0][mi][ni], 0, 0, 0);
        }
      __builtin_amdgcn_s_setprio(0);
      BAR;

      // ---- ph2: read B(qn1); stage K(t+2).A{0,2}; MFMA quad(0,1) ----
      #pragma unroll
      for (int ni = 0; ni < 2; ++ni) {
        const char* p = Bb + bbase + (32 + ni * 16) * 128;
        b1[ni][0] = *(const bf16x8*)(p + sw0);
        b1[ni][1] = *(const bf16x8*)(p + sw1);
      }
      if (st) STAGE_H2(sA, Ab, 0, 2);
      BAR;
      __builtin_amdgcn_s_setprio(1);
      #pragma unroll
      for (int mi = 0; mi < 4; ++mi)
        #pragma unroll
        for (int ni = 0; ni < 2; ++ni) {
          acc[0][1][mi][ni] = __builtin_amdgcn_mfma_f32_16x16x32_bf16(b1[ni][0], a[mi][0], acc[0][1][mi][ni], 0, 0, 0);
          acc[0][1][mi][ni] = __builtin_amdgcn_mfma_f32_16x16x32_bf16(b1[ni][1], a[mi][1], acc[0][1][mi][ni], 0, 0, 0);
        }
      __builtin_amdgcn_s_setprio(0);
      BAR;

      // ---- ph3: read A(qm1); stage K(t+2).B{0,1}; MFMA quad(1,0) ----
      #pragma unroll
      for (int mi = 0; mi < 4; ++mi) {
        const char* p = Ab + abase + (64 + mi * 16) * 128;
        a[mi][0] = *(const bf16x8*)(p + sw0);
        a[mi][1] = *(const bf16x8*)(p + sw1);
      }
      if (st) STAGE_H2(sB, Bb, 0, 1);
      BAR;
      __builtin_amdgcn_s_setprio(1);
      #pragma unroll
      for (int mi = 0; mi < 4; ++mi)
        #pragma unroll
        for (int ni = 0; ni < 2; ++ni) {
          acc[1][0][mi][ni] = __builtin_amdgcn_mfma_f32_16x16x32_bf16(b0[ni][0], a[mi][0], acc[1][0][mi][ni], 0, 0, 0);
          acc[1][0][mi][ni] = __builtin_amdgcn_mfma_f32_16x16x32_bf16(b0[ni][1], a[mi][1], acc[1][0][mi][ni], 0, 0, 0);
        }
      __builtin_amdgcn_s_setprio(0);
      BAR;

      // ---- ph4: stage K(t+2).B{2,3}+A{1,3}; MFMA quad(1,1); counted vmcnt --
      if (st) { STAGE_H2(sB, Bb, 2, 3); STAGE_H2(sA, Ab, 1, 3); }
      BAR;
      __builtin_amdgcn_s_setprio(1);
      #pragma unroll
      for (int mi = 0; mi < 4; ++mi)
        #pragma unroll
        for (int ni = 0; ni < 2; ++ni) {
          acc[1][1][mi][ni] = __builtin_amdgcn_mfma_f32_16x16x32_bf16(b1[ni][0], a[mi][0], acc[1][1][mi][ni], 0, 0, 0);
          acc[1][1][mi][ni] = __builtin_amdgcn_mfma_f32_16x16x32_bf16(b1[ni][1], a[mi][1], acc[1][1][mi][ni], 0, 0, 0);
        }
      __builtin_amdgcn_s_setprio(0);
      // FIFO invariant: 8 in flight = K(t+2) whole. Boundary t==0 (j>0):
      //   [K1'(8), ST(32), K2'(8)] -> vmcnt(40) retires K1' only. Tail: drain.
      if (!st)               { asm volatile("s_waitcnt vmcnt(0)"  ::: "memory"); }
      else if (t == 0 && j)  { asm volatile("s_waitcnt vmcnt(40)" ::: "memory"); }
      else                   { asm volatile("s_waitcnt vmcnt(8)"  ::: "memory"); }
      BAR;

      sA += 64; sB += 64;                              // next K-tile source
      if (t == NT - 3) { sA = gAn; sB = gBn; }         // wrap to next tile's K0
      Ab = (char*)((uintptr_t)Ab ^ 65536u);            // toggle double buffer
    }

    // ---- epilogue: bias from LDS + 32 f32x4 stores (through L2) ----
    const char* bl = smem + 131072 + j * 1024;
    f32x4 bq[2][2];
    #pragma unroll
    for (int qn = 0; qn < 2; ++qn)
      #pragma unroll
      for (int ni = 0; ni < 2; ++ni)
        bq[qn][ni] = *reinterpret_cast<const f32x4*>(
            bl + (wn * 64 + qn * 32 + ni * 16 + q4 * 4) * 4);

    #pragma unroll
    for (int qm = 0; qm < 2; ++qm)
      #pragma unroll
      for (int mi = 0; mi < 4; ++mi) {
        const int m = m0 + wm * 128 + qm * 64 + mi * 16 + r15;
        const int bb_ = m >> 12, tt = m & 4095;
        float* orow = out + (size_t)bb_ * 8388608 + (size_t)tt * 128;
        #pragma unroll
        for (int qn = 0; qn < 2; ++qn)
          #pragma unroll
          for (int ni = 0; ni < 2; ++ni) {
            const int col = n0 + wn * 64 + qn * 32 + ni * 16 + q4 * 4;
            const int which = col >> 11, head = (col & 2047) >> 7, hd = col & 127;
            f32x4 v = acc[qm][qn][mi][ni] + bq[qn][ni];
            *reinterpret_cast<f32x4*>(orow + (size_t)which * 33554432 +
                                      (size_t)head * 524288 + hd) = v;
          }
      }

    m0 = m0n; n0 = n0n; gA = gAn; gB = gBn;   // advance to next tile
  }
  #undef STAGE_T
  #undef STAGE_H2
  #undef TILE_MAP
}

// ---------- Fallback: naive fp32 ----------
__global__ __launch_bounds__(256) void naive_qkv(const float* __restrict__ h,
                                                 const float* __restrict__ w,
                                                 const float* __restrict__ bias,
                                                 float* __restrict__ out) {
  const int m = blockIdx.x;
  const int n = blockIdx.y * 256 + threadIdx.x;
  const float* hr = h + (size_t)m * K_DIM;
  float acc = bias[n];
  for (int k = 0; k < K_DIM; ++k) acc = fmaf(hr[k], w[(size_t)k * N_DIM + n], acc);
  const int which = n >> 11, head = (n & 2047) >> 7, hd = n & 127;
  const int bb = m >> 12, tt = m & 4095;
  out[(size_t)which * 33554432 + (size_t)bb * 8388608 + (size_t)head * 524288 +
      (size_t)tt * 128 + hd] = acc;
}

extern "C" void kernel_launch(void* const* d_in, const int* in_sizes, int n_in,
                              void* d_out, int out_size, void* d_ws, size_t ws_size,
                              hipStream_t stream) {
  const float* hidden = (const float*)d_in[0];
  const float* w_qkv  = (const float*)d_in[1];
  const float* b_qkv  = (const float*)d_in[2];
  float* out = (float*)d_out;

  const size_t needA = (size_t)M_DIM * K_DIM * 2;
  const size_t needB = (size_t)N_DIM * K_DIM * 2;
  if (ws_size >= needA + needB) {
    unsigned short* Abf = (unsigned short*)d_ws;
    unsigned short* Wt  = (unsigned short*)((char*)d_ws + needA);
    (void)hipFuncSetAttribute((const void*)gemm_qkv_8ph,
                              hipFuncAttributeMaxDynamicSharedMemorySize, 137216);
    cvt_fused<<<5120, 256, 0, stream>>>(hidden, Abf, w_qkv, Wt);
    gemm_qkv_8ph<<<256, 512, 137216, stream>>>(Abf, Wt, b_qkv, out);
  } else {
    naive_qkv<<<dim3(16384, 24), 256, 0, stream>>>(hidden, w_qkv, b_qkv, out);
  }
}

// Round 13
// 443.619 us; speedup vs baseline: 1.6485x; 1.6485x over previous
//
#include <hip/hip_runtime.h>
#include <hip/hip_bf16.h>
#include <stdint.h>

#define M_DIM 16384   // B*T = 4*4096
#define K_DIM 2048    // H
#define N_DIM 6144    // 3H
#define NT    32      // K-tiles per output tile (K_DIM/64)
#define NTILES 6      // output tiles per persistent block (1536/256)

typedef __attribute__((ext_vector_type(8))) short bf16x8;
typedef __attribute__((ext_vector_type(8))) unsigned short u16x8;
typedef __attribute__((ext_vector_type(4))) float f32x4;

__device__ __forceinline__ unsigned short f2bf(float f) {
  unsigned int u = __float_as_uint(f);
  u += 0x7FFFu + ((u >> 16) & 1u);   // RNE
  return (unsigned short)(u >> 16);
}

__device__ __forceinline__ void load_lds16(const void* g, void* l) {
  __builtin_amdgcn_global_load_lds((const __attribute__((address_space(1))) void*)g,
                                   (__attribute__((address_space(3))) void*)l, 16, 0, 0);
}

#define FENCE asm volatile("" ::: "memory")
#define BAR   do { FENCE; __builtin_amdgcn_s_barrier(); FENCE; } while (0)

// ---------- Pass 1: fused input conversion ----------
// blocks [0,2048): hidden fp32 -> bf16 straight copy (NT loads).
// blocks [2048,5120): w_qkv [K][N] -> Wt [N][K] bf16 transpose via LDS.
__global__ __launch_bounds__(256) void cvt_fused(const float* __restrict__ hidden,
                                                 unsigned short* __restrict__ outh,
                                                 const float* __restrict__ w,
                                                 unsigned short* __restrict__ wt) {
  __shared__ float tile[64][69];
  const int bid = blockIdx.x;
  const int t = threadIdx.x;
  if (bid < 2048) {
    unsigned int base = bid * 256u + t;
    #pragma unroll
    for (int i = 0; i < 16; ++i) {
      unsigned int fi = i * 524288u + base;
      f32x4 v = __builtin_nontemporal_load(reinterpret_cast<const f32x4*>(hidden) + fi);
      ushort4 o;
      o.x = f2bf(v[0]); o.y = f2bf(v[1]); o.z = f2bf(v[2]); o.w = f2bf(v[3]);
      reinterpret_cast<ushort4*>(outh)[fi] = o;
    }
  } else {
    const int wb = bid - 2048;                  // 0..3071
    const int k0 = (wb / 96) * 64;              // 32 k-tiles
    const int n0 = (wb % 96) * 64;              // 96 n-tiles
    #pragma unroll
    for (int i = 0; i < 4; ++i) {
      int idx = i * 256 + t;
      int row = idx >> 4, c4 = idx & 15;
      f32x4 v = __builtin_nontemporal_load(reinterpret_cast<const f32x4*>(
          &w[(size_t)(k0 + row) * N_DIM + n0 + c4 * 4]));
      tile[row][c4 * 4 + 0] = v[0]; tile[row][c4 * 4 + 1] = v[1];
      tile[row][c4 * 4 + 2] = v[2]; tile[row][c4 * 4 + 3] = v[3];
    }
    __syncthreads();
    #pragma unroll
    for (int i = 0; i < 2; ++i) {
      int idx = i * 256 + t;
      int n = idx >> 3, k8 = idx & 7;
      u16x8 v;
      #pragma unroll
      for (int e = 0; e < 8; ++e) v[e] = f2bf(tile[k8 * 8 + e][n]);
      *reinterpret_cast<u16x8*>(&wt[(size_t)(n0 + n) * K_DIM + k0 + k8 * 8]) = v;
    }
  }
}

// ---------- Pass 2: persistent seamless 256x256x64 8-phase bf16 MFMA GEMM ----
// R13 = R11 EXACTLY (best passing: 443.0us total) + one delta: steady wait
//   vmcnt(6) -> vmcnt(8). FIFO invariant: at ph4 the queue is [K(t+1):8,
//   K(t+2):8]; vmcnt(8) retires exactly K(t+1) and never touches K(t+2).
// R12's lesson: the (t&1)*65536 buffer select + ternary staging sources are
//   LOAD-BEARING — the compiler unrolls the t-loop by 2 and folds every LDS
//   address to a compile-time constant. Loop-carried pointers broke that
//   (-65% perf). Do not "optimize" the addressing.
// Rest: no manual lgkm drains (compiler emits fine-grained lgkmcnt); stage
//   spreading ph2 A{0,2} / ph3 B{0,1} / ph4 B{2,3}+A{1,3}; boundary vmcnt(40);
//   stores through L2; bias in LDS; swapped-operand MFMA -> f32x4 stores.
__global__ __launch_bounds__(512, 2) void gemm_qkv_8ph(const unsigned short* __restrict__ A,
                                                       const unsigned short* __restrict__ Bt,
                                                       const float* __restrict__ bias,
                                                       float* __restrict__ out) {
  extern __shared__ __align__(16) char smem[];
  const int tid = threadIdx.x, lane = tid & 63, wid = tid >> 6;
  const int wm = wid >> 2, wn = wid & 3;        // 2 x 4 wave grid, 128x64 per wave

  const int xcd = blockIdx.x & 7;
  const int lcl = blockIdx.x >> 3;              // 0..31 within XCD

  const int srow  = tid >> 3;
  const int sslot = (tid & 7) ^ ((tid >> 3) & 7);
  const int r15 = lane & 15, q4 = lane >> 4, x7 = lane & 7;
  const int abase = (wm * 128 + r15) * 128;
  const int bbase = (wn * 64  + r15) * 128;
  const int sw0 = ((0 + q4) ^ x7) * 16;
  const int sw1 = ((4 + q4) ^ x7) * 16;

  // full-tile stage (prologue only): 4 x gload_lds(16B)/thread
  #define STAGE_T(gsrc, ldsbase)                                              \
    { const unsigned short* _g = (gsrc); char* _l = (ldsbase);                \
      load_lds16(_g,                       _l +     wid * 1024);              \
      load_lds16(_g + (size_t)64  * K_DIM, _l + 8192  + wid * 1024);          \
      load_lds16(_g + (size_t)128 * K_DIM, _l + 16384 + wid * 1024);          \
      load_lds16(_g + (size_t)192 * K_DIM, _l + 24576 + wid * 1024); }

  // half-tile stage: chunks cA,cB (each chunk = 64 rows = 8KB)
  #define STAGE_H2(gsrc, ldsbase, cA, cB)                                     \
    { const unsigned short* _g = (gsrc); char* _l = (ldsbase);                \
      load_lds16(_g + (size_t)((cA) * 64) * K_DIM, _l + (cA) * 8192 + wid * 1024); \
      load_lds16(_g + (size_t)((cB) * 64) * K_DIM, _l + (cB) * 8192 + wid * 1024); }

  #define TILE_MAP(jj, m0_, n0_, gA_, gB_)                                    \
    { const int bm_ = xcd * 8 + (lcl >> 2);                                   \
      const int bn_ = (jj) * 4 + (lcl & 3);                                   \
      m0_ = bm_ * 256; n0_ = bn_ * 256;                                       \
      gA_ = A  + (size_t)(m0_ + srow) * K_DIM + sslot * 8;                    \
      gB_ = Bt + (size_t)(n0_ + srow) * K_DIM + sslot * 8; }

  // ---- bias preload into LDS corner (once): 6 tiles x 256 floats ----
  if (tid < 384) {
    const int jj = tid / 64;
    const int o  = (tid & 63) * 4;
    const int bn_ = jj * 4 + (lcl & 3);
    f32x4 bv = *reinterpret_cast<const f32x4*>(&bias[bn_ * 256 + o]);
    *reinterpret_cast<f32x4*>(smem + 131072 + jj * 1024 + o * 4) = bv;
  }

  // ---- first-tile prologue: K0 + K1 (16 loads), vmcnt(8) => K0 landed ----
  int m0, n0, m0n, n0n;
  const unsigned short *gA, *gB, *gAn, *gBn;
  TILE_MAP(0, m0, n0, gA, gB);
  {
    char* A0 = smem;          char* B0 = smem + 32768;
    char* A1 = smem + 65536;  char* B1 = smem + 98304;
    STAGE_T(gB +  0, B0); STAGE_T(gA +  0, A0);
    STAGE_T(gB + 64, B1); STAGE_T(gA + 64, A1);
    asm volatile("s_waitcnt vmcnt(8)" ::: "memory");
    BAR;
  }

  for (int j = 0; j < NTILES; ++j) {
    const int jn = (j + 1 < NTILES) ? j + 1 : j;
    TILE_MAP(jn, m0n, n0n, gAn, gBn);

    f32x4 acc[2][2][4][2] = {};                        // [qm][qn][mi][ni]
    bf16x8 a[4][2], b0[2][2], b1[2][2];

    for (int t = 0; t < NT; ++t) {
      char* Ab = smem + (t & 1) * 65536;
      char* Bb = Ab + 32768;
      const bool st = (t + 2 < NT) || (j + 1 < NTILES);
      const unsigned short* sA = (t + 2 < NT) ? gA + (size_t)(t + 2) * 64
                                              : gAn + (size_t)(t + 2 - NT) * 64;
      const unsigned short* sB = (t + 2 < NT) ? gB + (size_t)(t + 2) * 64
                                              : gBn + (size_t)(t + 2 - NT) * 64;

      // ---- ph1: read A(qm0)+B(qn0); MFMA quad(0,0) ----
      #pragma unroll
      for (int mi = 0; mi < 4; ++mi) {
        const char* p = Ab + abase + mi * (16 * 128);
        a[mi][0] = *(const bf16x8*)(p + sw0);
        a[mi][1] = *(const bf16x8*)(p + sw1);
      }
      #pragma unroll
      for (int ni = 0; ni < 2; ++ni) {
        const char* p = Bb + bbase + ni * (16 * 128);
        b0[ni][0] = *(const bf16x8*)(p + sw0);
        b0[ni][1] = *(const bf16x8*)(p + sw1);
      }
      BAR;
      __builtin_amdgcn_s_setprio(1);
      #pragma unroll
      for (int mi = 0; mi < 4; ++mi)
        #pragma unroll
        for (int ni = 0; ni < 2; ++ni) {
          acc[0][0][mi][ni] = __builtin_amdgcn_mfma_f32_16x16x32_bf16(b0[ni][0], a[mi][0], acc[0][0][mi][ni], 0, 0, 0);
          acc[0][0][mi][ni] = __builtin_amdgcn_mfma_f32_16x16x32_bf16(b0[ni][1], a[mi][1], acc[0][0][mi][ni], 0, 0, 0);
        }
      __builtin_amdgcn_s_setprio(0);
      BAR;

      // ---- ph2: read B(qn1); stage K(t+2).A{0,2}; MFMA quad(0,1) ----
      #pragma unroll
      for (int ni = 0; ni < 2; ++ni) {
        const char* p = Bb + bbase + (32 + ni * 16) * 128;
        b1[ni][0] = *(const bf16x8*)(p + sw0);
        b1[ni][1] = *(const bf16x8*)(p + sw1);
      }
      if (st) STAGE_H2(sA, Ab, 0, 2);
      BAR;
      __builtin_amdgcn_s_setprio(1);
      #pragma unroll
      for (int mi = 0; mi < 4; ++mi)
        #pragma unroll
        for (int ni = 0; ni < 2; ++ni) {
          acc[0][1][mi][ni] = __builtin_amdgcn_mfma_f32_16x16x32_bf16(b1[ni][0], a[mi][0], acc[0][1][mi][ni], 0, 0, 0);
          acc[0][1][mi][ni] = __builtin_amdgcn_mfma_f32_16x16x32_bf16(b1[ni][1], a[mi][1], acc[0][1][mi][ni], 0, 0, 0);
        }
      __builtin_amdgcn_s_setprio(0);
      BAR;

      // ---- ph3: read A(qm1); stage K(t+2).B{0,1}; MFMA quad(1,0) ----
      #pragma unroll
      for (int mi = 0; mi < 4; ++mi) {
        const char* p = Ab + abase + (64 + mi * 16) * 128;
        a[mi][0] = *(const bf16x8*)(p + sw0);
        a[mi][1] = *(const bf16x8*)(p + sw1);
      }
      if (st) STAGE_H2(sB, Bb, 0, 1);
      BAR;
      __builtin_amdgcn_s_setprio(1);
      #pragma unroll
      for (int mi = 0; mi < 4; ++mi)
        #pragma unroll
        for (int ni = 0; ni < 2; ++ni) {
          acc[1][0][mi][ni] = __builtin_amdgcn_mfma_f32_16x16x32_bf16(b0[ni][0], a[mi][0], acc[1][0][mi][ni], 0, 0, 0);
          acc[1][0][mi][ni] = __builtin_amdgcn_mfma_f32_16x16x32_bf16(b0[ni][1], a[mi][1], acc[1][0][mi][ni], 0, 0, 0);
        }
      __builtin_amdgcn_s_setprio(0);
      BAR;

      // ---- ph4: stage K(t+2).B{2,3}+A{1,3}; MFMA quad(1,1); counted vmcnt --
      if (st) { STAGE_H2(sB, Bb, 2, 3); STAGE_H2(sA, Ab, 1, 3); }
      BAR;
      __builtin_amdgcn_s_setprio(1);
      #pragma unroll
      for (int mi = 0; mi < 4; ++mi)
        #pragma unroll
        for (int ni = 0; ni < 2; ++ni) {
          acc[1][1][mi][ni] = __builtin_amdgcn_mfma_f32_16x16x32_bf16(b1[ni][0], a[mi][0], acc[1][1][mi][ni], 0, 0, 0);
          acc[1][1][mi][ni] = __builtin_amdgcn_mfma_f32_16x16x32_bf16(b1[ni][1], a[mi][1], acc[1][1][mi][ni], 0, 0, 0);
        }
      __builtin_amdgcn_s_setprio(0);
      // t==0 (j>0): younger = ST(32)+K(t+2)(8) => vmcnt(40) -> K(t+1) done,
      //   stores in flight. Steady: vmcnt(8) = exact K(t+2)-in-flight
      //   invariant. Tail: full drain.
      if (t == 0 && j != 0)  { asm volatile("s_waitcnt vmcnt(40)" ::: "memory"); }
      else if (st)           { asm volatile("s_waitcnt vmcnt(8)"  ::: "memory"); }
      else                   { asm volatile("s_waitcnt vmcnt(0)"  ::: "memory"); }
      BAR;
    }

    // ---- epilogue: bias from LDS + 32 f32x4 stores (through L2) ----
    const char* bl = smem + 131072 + j * 1024;
    f32x4 bq[2][2];
    #pragma unroll
    for (int qn = 0; qn < 2; ++qn)
      #pragma unroll
      for (int ni = 0; ni < 2; ++ni)
        bq[qn][ni] = *reinterpret_cast<const f32x4*>(
            bl + (wn * 64 + qn * 32 + ni * 16 + q4 * 4) * 4);

    #pragma unroll
    for (int qm = 0; qm < 2; ++qm)
      #pragma unroll
      for (int mi = 0; mi < 4; ++mi) {
        const int m = m0 + wm * 128 + qm * 64 + mi * 16 + r15;
        const int bb_ = m >> 12, tt = m & 4095;
        float* orow = out + (size_t)bb_ * 8388608 + (size_t)tt * 128;
        #pragma unroll
        for (int qn = 0; qn < 2; ++qn)
          #pragma unroll
          for (int ni = 0; ni < 2; ++ni) {
            const int col = n0 + wn * 64 + qn * 32 + ni * 16 + q4 * 4;
            const int which = col >> 11, head = (col & 2047) >> 7, hd = col & 127;
            f32x4 v = acc[qm][qn][mi][ni] + bq[qn][ni];
            *reinterpret_cast<f32x4*>(orow + (size_t)which * 33554432 +
                                      (size_t)head * 524288 + hd) = v;
          }
      }

    m0 = m0n; n0 = n0n; gA = gAn; gB = gBn;   // advance to next tile
  }
  #undef STAGE_T
  #undef STAGE_H2
  #undef TILE_MAP
}

// ---------- Fallback: naive fp32 ----------
__global__ __launch_bounds__(256) void naive_qkv(const float* __restrict__ h,
                                                 const float* __restrict__ w,
                                                 const float* __restrict__ bias,
                                                 float* __restrict__ out) {
  const int m = blockIdx.x;
  const int n = blockIdx.y * 256 + threadIdx.x;
  const float* hr = h + (size_t)m * K_DIM;
  float acc = bias[n];
  for (int k = 0; k < K_DIM; ++k) acc = fmaf(hr[k], w[(size_t)k * N_DIM + n], acc);
  const int which = n >> 11, head = (n & 2047) >> 7, hd = n & 127;
  const int bb = m >> 12, tt = m & 4095;
  out[(size_t)which * 33554432 + (size_t)bb * 8388608 + (size_t)head * 524288 +
      (size_t)tt * 128 + hd] = acc;
}

extern "C" void kernel_launch(void* const* d_in, const int* in_sizes, int n_in,
                              void* d_out, int out_size, void* d_ws, size_t ws_size,
                              hipStream_t stream) {
  const float* hidden = (const float*)d_in[0];
  const float* w_qkv  = (const float*)d_in[1];
  const float* b_qkv  = (const float*)d_in[2];
  float* out = (float*)d_out;

  const size_t needA = (size_t)M_DIM * K_DIM * 2;
  const size_t needB = (size_t)N_DIM * K_DIM * 2;
  if (ws_size >= needA + needB) {
    unsigned short* Abf = (unsigned short*)d_ws;
    unsigned short* Wt  = (unsigned short*)((char*)d_ws + needA);
    (void)hipFuncSetAttribute((const void*)gemm_qkv_8ph,
                              hipFuncAttributeMaxDynamicSharedMemorySize, 137216);
    cvt_fused<<<5120, 256, 0, stream>>>(hidden, Abf, w_qkv, Wt);
    gemm_qkv_8ph<<<256, 512, 137216, stream>>>(Abf, Wt, b_qkv, out);
  } else {
    naive_qkv<<<dim3(16384, 24), 256, 0, stream>>>(hidden, w_qkv, b_qkv, out);
  }
}

// Round 14
// 441.032 us; speedup vs baseline: 1.6581x; 1.0059x over previous
//
#include <hip/hip_runtime.h>
#include <hip/hip_bf16.h>
#include <stdint.h>

#define M_DIM 16384   // B*T = 4*4096
#define K_DIM 2048    // H
#define N_DIM 6144    // 3H
#define NT    32      // K-tiles per output tile (K_DIM/64)
#define NTILES 6      // output tiles per persistent block (1536/256)

typedef __attribute__((ext_vector_type(8))) short bf16x8;
typedef __attribute__((ext_vector_type(8))) unsigned short u16x8;
typedef __attribute__((ext_vector_type(4))) float f32x4;

__device__ __forceinline__ unsigned short f2bf(float f) {
  unsigned int u = __float_as_uint(f);
  u += 0x7FFFu + ((u >> 16) & 1u);   // RNE
  return (unsigned short)(u >> 16);
}

__device__ __forceinline__ void load_lds16(const void* g, void* l) {
  __builtin_amdgcn_global_load_lds((const __attribute__((address_space(1))) void*)g,
                                   (__attribute__((address_space(3))) void*)l, 16, 0, 0);
}

#define FENCE asm volatile("" ::: "memory")
#define BAR   do { FENCE; __builtin_amdgcn_s_barrier(); FENCE; } while (0)

// ---------- Pass 1: fused input conversion ----------
// blocks [0,2048): hidden fp32 -> bf16 straight copy (NT loads).
// blocks [2048,5120): w_qkv [K][N] -> Wt [N][K] bf16 transpose via LDS.
__global__ __launch_bounds__(256) void cvt_fused(const float* __restrict__ hidden,
                                                 unsigned short* __restrict__ outh,
                                                 const float* __restrict__ w,
                                                 unsigned short* __restrict__ wt) {
  __shared__ float tile[64][69];
  const int bid = blockIdx.x;
  const int t = threadIdx.x;
  if (bid < 2048) {
    unsigned int base = bid * 256u + t;
    #pragma unroll
    for (int i = 0; i < 16; ++i) {
      unsigned int fi = i * 524288u + base;
      f32x4 v = __builtin_nontemporal_load(reinterpret_cast<const f32x4*>(hidden) + fi);
      ushort4 o;
      o.x = f2bf(v[0]); o.y = f2bf(v[1]); o.z = f2bf(v[2]); o.w = f2bf(v[3]);
      reinterpret_cast<ushort4*>(outh)[fi] = o;
    }
  } else {
    const int wb = bid - 2048;                  // 0..3071
    const int k0 = (wb / 96) * 64;              // 32 k-tiles
    const int n0 = (wb % 96) * 64;              // 96 n-tiles
    #pragma unroll
    for (int i = 0; i < 4; ++i) {
      int idx = i * 256 + t;
      int row = idx >> 4, c4 = idx & 15;
      f32x4 v = __builtin_nontemporal_load(reinterpret_cast<const f32x4*>(
          &w[(size_t)(k0 + row) * N_DIM + n0 + c4 * 4]));
      tile[row][c4 * 4 + 0] = v[0]; tile[row][c4 * 4 + 1] = v[1];
      tile[row][c4 * 4 + 2] = v[2]; tile[row][c4 * 4 + 3] = v[3];
    }
    __syncthreads();
    #pragma unroll
    for (int i = 0; i < 2; ++i) {
      int idx = i * 256 + t;
      int n = idx >> 3, k8 = idx & 7;
      u16x8 v;
      #pragma unroll
      for (int e = 0; e < 8; ++e) v[e] = f2bf(tile[k8 * 8 + e][n]);
      *reinterpret_cast<u16x8*>(&wt[(size_t)(n0 + n) * K_DIM + k0 + k8 * 8]) = v;
    }
  }
}

// ---------- Pass 2: persistent seamless 256x256x64 8-phase bf16 MFMA GEMM ----
// R14 = R13 + bias folded into accumulator init: with swapped operands
//   (mfma(b,a)) a lane's 4 acc regs are 4 consecutive n-cols, so
//   acc[qm][qn][mi][ni] = bias4[qn][ni] initializes every output row with its
//   column bias exactly once. Epilogue becomes pure f32x4 stores (no adds,
//   no LDS bias reads) — shortens the serialized boundary window ahead of
//   the store drain.
// R12's lesson: (t&1)*65536 buffer select + ternary staging sources are
//   LOAD-BEARING (compiler 2x-unrolls and folds LDS addresses). Don't touch.
// Rest: no manual lgkm drains; stage spreading ph2 A{0,2} / ph3 B{0,1} /
//   ph4 B{2,3}+A{1,3}; steady vmcnt(8) (exact FIFO invariant), boundary
//   vmcnt(40), tail vmcnt(0); stores through L2; swapped-operand MFMA.
__global__ __launch_bounds__(512, 2) void gemm_qkv_8ph(const unsigned short* __restrict__ A,
                                                       const unsigned short* __restrict__ Bt,
                                                       const float* __restrict__ bias,
                                                       float* __restrict__ out) {
  extern __shared__ __align__(16) char smem[];
  const int tid = threadIdx.x, lane = tid & 63, wid = tid >> 6;
  const int wm = wid >> 2, wn = wid & 3;        // 2 x 4 wave grid, 128x64 per wave

  const int xcd = blockIdx.x & 7;
  const int lcl = blockIdx.x >> 3;              // 0..31 within XCD

  const int srow  = tid >> 3;
  const int sslot = (tid & 7) ^ ((tid >> 3) & 7);
  const int r15 = lane & 15, q4 = lane >> 4, x7 = lane & 7;
  const int abase = (wm * 128 + r15) * 128;
  const int bbase = (wn * 64  + r15) * 128;
  const int sw0 = ((0 + q4) ^ x7) * 16;
  const int sw1 = ((4 + q4) ^ x7) * 16;

  // full-tile stage (prologue only): 4 x gload_lds(16B)/thread
  #define STAGE_T(gsrc, ldsbase)                                              \
    { const unsigned short* _g = (gsrc); char* _l = (ldsbase);                \
      load_lds16(_g,                       _l +     wid * 1024);              \
      load_lds16(_g + (size_t)64  * K_DIM, _l + 8192  + wid * 1024);          \
      load_lds16(_g + (size_t)128 * K_DIM, _l + 16384 + wid * 1024);          \
      load_lds16(_g + (size_t)192 * K_DIM, _l + 24576 + wid * 1024); }

  // half-tile stage: chunks cA,cB (each chunk = 64 rows = 8KB)
  #define STAGE_H2(gsrc, ldsbase, cA, cB)                                     \
    { const unsigned short* _g = (gsrc); char* _l = (ldsbase);                \
      load_lds16(_g + (size_t)((cA) * 64) * K_DIM, _l + (cA) * 8192 + wid * 1024); \
      load_lds16(_g + (size_t)((cB) * 64) * K_DIM, _l + (cB) * 8192 + wid * 1024); }

  #define TILE_MAP(jj, m0_, n0_, gA_, gB_)                                    \
    { const int bm_ = xcd * 8 + (lcl >> 2);                                   \
      const int bn_ = (jj) * 4 + (lcl & 3);                                   \
      m0_ = bm_ * 256; n0_ = bn_ * 256;                                       \
      gA_ = A  + (size_t)(m0_ + srow) * K_DIM + sslot * 8;                    \
      gB_ = Bt + (size_t)(n0_ + srow) * K_DIM + sslot * 8; }

  // ---- bias preload into LDS corner (once): 6 tiles x 256 floats ----
  if (tid < 384) {
    const int jj = tid / 64;
    const int o  = (tid & 63) * 4;
    const int bn_ = jj * 4 + (lcl & 3);
    f32x4 bv = *reinterpret_cast<const f32x4*>(&bias[bn_ * 256 + o]);
    *reinterpret_cast<f32x4*>(smem + 131072 + jj * 1024 + o * 4) = bv;
  }

  // ---- first-tile prologue: K0 + K1 (16 loads), vmcnt(8) => K0 landed ----
  int m0, n0, m0n, n0n;
  const unsigned short *gA, *gB, *gAn, *gBn;
  TILE_MAP(0, m0, n0, gA, gB);
  {
    char* A0 = smem;          char* B0 = smem + 32768;
    char* A1 = smem + 65536;  char* B1 = smem + 98304;
    STAGE_T(gB +  0, B0); STAGE_T(gA +  0, A0);
    STAGE_T(gB + 64, B1); STAGE_T(gA + 64, A1);
    asm volatile("s_waitcnt vmcnt(8)" ::: "memory");
    BAR;
  }

  for (int j = 0; j < NTILES; ++j) {
    const int jn = (j + 1 < NTILES) ? j + 1 : j;
    TILE_MAP(jn, m0n, n0n, gAn, gBn);

    // bias-as-acc-init: lane's 4 acc regs = 4 consecutive n-cols
    f32x4 bq[2][2];
    {
      const char* bl = smem + 131072 + j * 1024;
      #pragma unroll
      for (int qn = 0; qn < 2; ++qn)
        #pragma unroll
        for (int ni = 0; ni < 2; ++ni)
          bq[qn][ni] = *reinterpret_cast<const f32x4*>(
              bl + (wn * 64 + qn * 32 + ni * 16 + q4 * 4) * 4);
    }
    f32x4 acc[2][2][4][2];                             // [qm][qn][mi][ni]
    #pragma unroll
    for (int qm = 0; qm < 2; ++qm)
      #pragma unroll
      for (int qn = 0; qn < 2; ++qn)
        #pragma unroll
        for (int mi = 0; mi < 4; ++mi)
          #pragma unroll
          for (int ni = 0; ni < 2; ++ni)
            acc[qm][qn][mi][ni] = bq[qn][ni];

    bf16x8 a[4][2], b0[2][2], b1[2][2];

    for (int t = 0; t < NT; ++t) {
      char* Ab = smem + (t & 1) * 65536;
      char* Bb = Ab + 32768;
      const bool st = (t + 2 < NT) || (j + 1 < NTILES);
      const unsigned short* sA = (t + 2 < NT) ? gA + (size_t)(t + 2) * 64
                                              : gAn + (size_t)(t + 2 - NT) * 64;
      const unsigned short* sB = (t + 2 < NT) ? gB + (size_t)(t + 2) * 64
                                              : gBn + (size_t)(t + 2 - NT) * 64;

      // ---- ph1: read A(qm0)+B(qn0); MFMA quad(0,0) ----
      #pragma unroll
      for (int mi = 0; mi < 4; ++mi) {
        const char* p = Ab + abase + mi * (16 * 128);
        a[mi][0] = *(const bf16x8*)(p + sw0);
        a[mi][1] = *(const bf16x8*)(p + sw1);
      }
      #pragma unroll
      for (int ni = 0; ni < 2; ++ni) {
        const char* p = Bb + bbase + ni * (16 * 128);
        b0[ni][0] = *(const bf16x8*)(p + sw0);
        b0[ni][1] = *(const bf16x8*)(p + sw1);
      }
      BAR;
      __builtin_amdgcn_s_setprio(1);
      #pragma unroll
      for (int mi = 0; mi < 4; ++mi)
        #pragma unroll
        for (int ni = 0; ni < 2; ++ni) {
          acc[0][0][mi][ni] = __builtin_amdgcn_mfma_f32_16x16x32_bf16(b0[ni][0], a[mi][0], acc[0][0][mi][ni], 0, 0, 0);
          acc[0][0][mi][ni] = __builtin_amdgcn_mfma_f32_16x16x32_bf16(b0[ni][1], a[mi][1], acc[0][0][mi][ni], 0, 0, 0);
        }
      __builtin_amdgcn_s_setprio(0);
      BAR;

      // ---- ph2: read B(qn1); stage K(t+2).A{0,2}; MFMA quad(0,1) ----
      #pragma unroll
      for (int ni = 0; ni < 2; ++ni) {
        const char* p = Bb + bbase + (32 + ni * 16) * 128;
        b1[ni][0] = *(const bf16x8*)(p + sw0);
        b1[ni][1] = *(const bf16x8*)(p + sw1);
      }
      if (st) STAGE_H2(sA, Ab, 0, 2);
      BAR;
      __builtin_amdgcn_s_setprio(1);
      #pragma unroll
      for (int mi = 0; mi < 4; ++mi)
        #pragma unroll
        for (int ni = 0; ni < 2; ++ni) {
          acc[0][1][mi][ni] = __builtin_amdgcn_mfma_f32_16x16x32_bf16(b1[ni][0], a[mi][0], acc[0][1][mi][ni], 0, 0, 0);
          acc[0][1][mi][ni] = __builtin_amdgcn_mfma_f32_16x16x32_bf16(b1[ni][1], a[mi][1], acc[0][1][mi][ni], 0, 0, 0);
        }
      __builtin_amdgcn_s_setprio(0);
      BAR;

      // ---- ph3: read A(qm1); stage K(t+2).B{0,1}; MFMA quad(1,0) ----
      #pragma unroll
      for (int mi = 0; mi < 4; ++mi) {
        const char* p = Ab + abase + (64 + mi * 16) * 128;
        a[mi][0] = *(const bf16x8*)(p + sw0);
        a[mi][1] = *(const bf16x8*)(p + sw1);
      }
      if (st) STAGE_H2(sB, Bb, 0, 1);
      BAR;
      __builtin_amdgcn_s_setprio(1);
      #pragma unroll
      for (int mi = 0; mi < 4; ++mi)
        #pragma unroll
        for (int ni = 0; ni < 2; ++ni) {
          acc[1][0][mi][ni] = __builtin_amdgcn_mfma_f32_16x16x32_bf16(b0[ni][0], a[mi][0], acc[1][0][mi][ni], 0, 0, 0);
          acc[1][0][mi][ni] = __builtin_amdgcn_mfma_f32_16x16x32_bf16(b0[ni][1], a[mi][1], acc[1][0][mi][ni], 0, 0, 0);
        }
      __builtin_amdgcn_s_setprio(0);
      BAR;

      // ---- ph4: stage K(t+2).B{2,3}+A{1,3}; MFMA quad(1,1); counted vmcnt --
      if (st) { STAGE_H2(sB, Bb, 2, 3); STAGE_H2(sA, Ab, 1, 3); }
      BAR;
      __builtin_amdgcn_s_setprio(1);
      #pragma unroll
      for (int mi = 0; mi < 4; ++mi)
        #pragma unroll
        for (int ni = 0; ni < 2; ++ni) {
          acc[1][1][mi][ni] = __builtin_amdgcn_mfma_f32_16x16x32_bf16(b1[ni][0], a[mi][0], acc[1][1][mi][ni], 0, 0, 0);
          acc[1][1][mi][ni] = __builtin_amdgcn_mfma_f32_16x16x32_bf16(b1[ni][1], a[mi][1], acc[1][1][mi][ni], 0, 0, 0);
        }
      __builtin_amdgcn_s_setprio(0);
      // t==0 (j>0): younger = ST(32)+K(t+2)(8) => vmcnt(40) -> K(t+1) done,
      //   stores in flight. Steady: vmcnt(8) = exact K(t+2)-in-flight
      //   invariant. Tail: full drain.
      if (t == 0 && j != 0)  { asm volatile("s_waitcnt vmcnt(40)" ::: "memory"); }
      else if (st)           { asm volatile("s_waitcnt vmcnt(8)"  ::: "memory"); }
      else                   { asm volatile("s_waitcnt vmcnt(0)"  ::: "memory"); }
      BAR;
    }

    // ---- epilogue: 32 pure f32x4 stores (bias already in acc) ----
    #pragma unroll
    for (int qm = 0; qm < 2; ++qm)
      #pragma unroll
      for (int mi = 0; mi < 4; ++mi) {
        const int m = m0 + wm * 128 + qm * 64 + mi * 16 + r15;
        const int bb_ = m >> 12, tt = m & 4095;
        float* orow = out + (size_t)bb_ * 8388608 + (size_t)tt * 128;
        #pragma unroll
        for (int qn = 0; qn < 2; ++qn)
          #pragma unroll
          for (int ni = 0; ni < 2; ++ni) {
            const int col = n0 + wn * 64 + qn * 32 + ni * 16 + q4 * 4;
            const int which = col >> 11, head = (col & 2047) >> 7, hd = col & 127;
            *reinterpret_cast<f32x4*>(orow + (size_t)which * 33554432 +
                                      (size_t)head * 524288 + hd) = acc[qm][qn][mi][ni];
          }
      }

    m0 = m0n; n0 = n0n; gA = gAn; gB = gBn;   // advance to next tile
  }
  #undef STAGE_T
  #undef STAGE_H2
  #undef TILE_MAP
}

// ---------- Fallback: naive fp32 ----------
__global__ __launch_bounds__(256) void naive_qkv(const float* __restrict__ h,
                                                 const float* __restrict__ w,
                                                 const float* __restrict__ bias,
                                                 float* __restrict__ out) {
  const int m = blockIdx.x;
  const int n = blockIdx.y * 256 + threadIdx.x;
  const float* hr = h + (size_t)m * K_DIM;
  float acc = bias[n];
  for (int k = 0; k < K_DIM; ++k) acc = fmaf(hr[k], w[(size_t)k * N_DIM + n], acc);
  const int which = n >> 11, head = (n & 2047) >> 7, hd = n & 127;
  const int bb = m >> 12, tt = m & 4095;
  out[(size_t)which * 33554432 + (size_t)bb * 8388608 + (size_t)head * 524288 +
      (size_t)tt * 128 + hd] = acc;
}

extern "C" void kernel_launch(void* const* d_in, const int* in_sizes, int n_in,
                              void* d_out, int out_size, void* d_ws, size_t ws_size,
                              hipStream_t stream) {
  const float* hidden = (const float*)d_in[0];
  const float* w_qkv  = (const float*)d_in[1];
  const float* b_qkv  = (const float*)d_in[2];
  float* out = (float*)d_out;

  const size_t needA = (size_t)M_DIM * K_DIM * 2;
  const size_t needB = (size_t)N_DIM * K_DIM * 2;
  if (ws_size >= needA + needB) {
    unsigned short* Abf = (unsigned short*)d_ws;
    unsigned short* Wt  = (unsigned short*)((char*)d_ws + needA);
    (void)hipFuncSetAttribute((const void*)gemm_qkv_8ph,
                              hipFuncAttributeMaxDynamicSharedMemorySize, 137216);
    cvt_fused<<<5120, 256, 0, stream>>>(hidden, Abf, w_qkv, Wt);
    gemm_qkv_8ph<<<256, 512, 137216, stream>>>(Abf, Wt, b_qkv, out);
  } else {
    naive_qkv<<<dim3(16384, 24), 256, 0, stream>>>(hidden, w_qkv, b_qkv, out);
  }
}

// Round 15
// 433.736 us; speedup vs baseline: 1.6860x; 1.0168x over previous
//
#include <hip/hip_runtime.h>
#include <hip/hip_bf16.h>
#include <stdint.h>

#define M_DIM 16384   // B*T = 4*4096
#define K_DIM 2048    // H
#define N_DIM 6144    // 3H
#define NT    32      // K-tiles per output tile (K_DIM/64)
#define NTILES 6      // output tiles per persistent block (1536/256)

typedef __attribute__((ext_vector_type(8))) short bf16x8;
typedef __attribute__((ext_vector_type(8))) unsigned short u16x8;
typedef __attribute__((ext_vector_type(4))) float f32x4;

__device__ __forceinline__ unsigned short f2bf(float f) {
  unsigned int u = __float_as_uint(f);
  u += 0x7FFFu + ((u >> 16) & 1u);   // RNE
  return (unsigned short)(u >> 16);
}

__device__ __forceinline__ void load_lds16(const void* g, void* l) {
  __builtin_amdgcn_global_load_lds((const __attribute__((address_space(1))) void*)g,
                                   (__attribute__((address_space(3))) void*)l, 16, 0, 0);
}

#define FENCE asm volatile("" ::: "memory")
#define BAR   do { FENCE; __builtin_amdgcn_s_barrier(); FENCE; } while (0)

// ---------- Pass 1: fused input conversion ----------
__global__ __launch_bounds__(256) void cvt_fused(const float* __restrict__ hidden,
                                                 unsigned short* __restrict__ outh,
                                                 const float* __restrict__ w,
                                                 unsigned short* __restrict__ wt) {
  __shared__ float tile[64][69];
  const int bid = blockIdx.x;
  const int t = threadIdx.x;
  if (bid < 2048) {
    unsigned int base = bid * 256u + t;
    #pragma unroll
    for (int i = 0; i < 16; ++i) {
      unsigned int fi = i * 524288u + base;
      f32x4 v = __builtin_nontemporal_load(reinterpret_cast<const f32x4*>(hidden) + fi);
      ushort4 o;
      o.x = f2bf(v[0]); o.y = f2bf(v[1]); o.z = f2bf(v[2]); o.w = f2bf(v[3]);
      reinterpret_cast<ushort4*>(outh)[fi] = o;
    }
  } else {
    const int wb = bid - 2048;                  // 0..3071
    const int k0 = (wb / 96) * 64;
    const int n0 = (wb % 96) * 64;
    #pragma unroll
    for (int i = 0; i < 4; ++i) {
      int idx = i * 256 + t;
      int row = idx >> 4, c4 = idx & 15;
      f32x4 v = __builtin_nontemporal_load(reinterpret_cast<const f32x4*>(
          &w[(size_t)(k0 + row) * N_DIM + n0 + c4 * 4]));
      tile[row][c4 * 4 + 0] = v[0]; tile[row][c4 * 4 + 1] = v[1];
      tile[row][c4 * 4 + 2] = v[2]; tile[row][c4 * 4 + 3] = v[3];
    }
    __syncthreads();
    #pragma unroll
    for (int i = 0; i < 2; ++i) {
      int idx = i * 256 + t;
      int n = idx >> 3, k8 = idx & 7;
      u16x8 v;
      #pragma unroll
      for (int e = 0; e < 8; ++e) v[e] = f2bf(tile[k8 * 8 + e][n]);
      *reinterpret_cast<u16x8*>(&wt[(size_t)(n0 + n) * K_DIM + k0 + k8 * 8]) = v;
    }
  }
}

// ---------- Pass 2: persistent 256x256x64 **2-phase** bf16 MFMA GEMM ----------
// R15 = R14 with the K-iter merged from 4 phases (8 barriers) to 2 phases
//   (4 barriers), keeping the read||stage||MFMA interleave:
//   ph_A: read B(all 8) + A-lo(8); stage K(t+1).A{1,3} -> buf[(t+1)&1];
//         BAR; 32 MFMA (qm=0); BAR.
//   ph_B: read A-hi(8); stage K(t+2).B{0-3}+A{0,2} -> buf[t&1];
//         BAR; 32 MFMA (qm=1); vmcnt; BAR.
// Staging safety (same invariant as m201): a region is staged only in a
//   phase AFTER the barrier following its last read:
//   - K(t+1).A{1,3} @ t.phA: buf[(t+1)&1].A-hi last read at (t-1).phB (ds
//     reads precede that phase's BAR; staging issues after it). 1-barrier gap.
//   - K(t+2).B / A{0,2} @ t.phB: same-buffer B and A-lo last read at t.phA;
//     2 barriers + MFMA cluster between.
// vmcnt: 8 staging ops/iter (phA 2 + phB 6). At phB end the queue is
//   [t.phA(2)=K(t+1).A13, t.phB(6)=K(t+2)] -> vmcnt(6) guarantees K(t+1)
//   complete. UNIFORM for all iters incl. t==0 (boundary stores, older in
//   FIFO, retire by then — acceptable). Tail (st2 false): vmcnt(0).
// Prologue: K0 full (8) + K1.B{0-3}+A{0,2} (6); vmcnt(6); BAR. t=0.phA
//   stages K1.A{1,3} — chain is seamless across tiles (t=31.phA stages
//   K0n.A13, t=31.phB stages K1n.B+A02).
// Bias folded into acc-init; epilogue = 32 pure f32x4 stores through L2.
// (R12 lesson: (t&1) selects + ternary sources are load-bearing — kept.)
__global__ __launch_bounds__(512, 2) void gemm_qkv_8ph(const unsigned short* __restrict__ A,
                                                       const unsigned short* __restrict__ Bt,
                                                       const float* __restrict__ bias,
                                                       float* __restrict__ out) {
  extern __shared__ __align__(16) char smem[];
  const int tid = threadIdx.x, lane = tid & 63, wid = tid >> 6;
  const int wm = wid >> 2, wn = wid & 3;        // 2 x 4 wave grid, 128x64 per wave

  const int xcd = blockIdx.x & 7;
  const int lcl = blockIdx.x >> 3;              // 0..31 within XCD

  const int srow  = tid >> 3;
  const int sslot = (tid & 7) ^ ((tid >> 3) & 7);
  const int r15 = lane & 15, q4 = lane >> 4, x7 = lane & 7;
  const int abase = (wm * 128 + r15) * 128;
  const int bbase = (wn * 64  + r15) * 128;
  const int sw0 = ((0 + q4) ^ x7) * 16;
  const int sw1 = ((4 + q4) ^ x7) * 16;

  #define STAGE_T(gsrc, ldsbase)                                              \
    { const unsigned short* _g = (gsrc); char* _l = (ldsbase);                \
      load_lds16(_g,                       _l +     wid * 1024);              \
      load_lds16(_g + (size_t)64  * K_DIM, _l + 8192  + wid * 1024);          \
      load_lds16(_g + (size_t)128 * K_DIM, _l + 16384 + wid * 1024);          \
      load_lds16(_g + (size_t)192 * K_DIM, _l + 24576 + wid * 1024); }

  #define STAGE_H2(gsrc, ldsbase, cA, cB)                                     \
    { const unsigned short* _g = (gsrc); char* _l = (ldsbase);                \
      load_lds16(_g + (size_t)((cA) * 64) * K_DIM, _l + (cA) * 8192 + wid * 1024); \
      load_lds16(_g + (size_t)((cB) * 64) * K_DIM, _l + (cB) * 8192 + wid * 1024); }

  #define TILE_MAP(jj, m0_, n0_, gA_, gB_)                                    \
    { const int bm_ = xcd * 8 + (lcl >> 2);                                   \
      const int bn_ = (jj) * 4 + (lcl & 3);                                   \
      m0_ = bm_ * 256; n0_ = bn_ * 256;                                       \
      gA_ = A  + (size_t)(m0_ + srow) * K_DIM + sslot * 8;                    \
      gB_ = Bt + (size_t)(n0_ + srow) * K_DIM + sslot * 8; }

  // ---- bias preload into LDS corner (once): 6 tiles x 256 floats ----
  if (tid < 384) {
    const int jj = tid / 64;
    const int o  = (tid & 63) * 4;
    const int bn_ = jj * 4 + (lcl & 3);
    f32x4 bv = *reinterpret_cast<const f32x4*>(&bias[bn_ * 256 + o]);
    *reinterpret_cast<f32x4*>(smem + 131072 + jj * 1024 + o * 4) = bv;
  }

  // ---- prologue: K0 full (8) + K1 partial B{0-3}+A{0,2} (6) ----
  int m0, n0, m0n, n0n;
  const unsigned short *gA, *gB, *gAn, *gBn;
  TILE_MAP(0, m0, n0, gA, gB);
  {
    char* A0 = smem;          char* B0 = smem + 32768;
    char* A1 = smem + 65536;  char* B1 = smem + 98304;
    STAGE_T(gB +  0, B0); STAGE_T(gA +  0, A0);
    STAGE_H2(gB + 64, B1, 0, 1); STAGE_H2(gB + 64, B1, 2, 3);
    STAGE_H2(gA + 64, A1, 0, 2);
    asm volatile("s_waitcnt vmcnt(6)" ::: "memory");   // K0 landed
    BAR;
  }

  for (int j = 0; j < NTILES; ++j) {
    const int jn = (j + 1 < NTILES) ? j + 1 : j;
    TILE_MAP(jn, m0n, n0n, gAn, gBn);

    // bias-as-acc-init: lane's 4 acc regs = 4 consecutive n-cols
    f32x4 bq[2][2];
    {
      const char* bl = smem + 131072 + j * 1024;
      #pragma unroll
      for (int qn = 0; qn < 2; ++qn)
        #pragma unroll
        for (int ni = 0; ni < 2; ++ni)
          bq[qn][ni] = *reinterpret_cast<const f32x4*>(
              bl + (wn * 64 + qn * 32 + ni * 16 + q4 * 4) * 4);
    }
    f32x4 acc[2][2][4][2];                             // [qm][qn][mi][ni]
    #pragma unroll
    for (int qm = 0; qm < 2; ++qm)
      #pragma unroll
      for (int qn = 0; qn < 2; ++qn)
        #pragma unroll
        for (int mi = 0; mi < 4; ++mi)
          #pragma unroll
          for (int ni = 0; ni < 2; ++ni)
            acc[qm][qn][mi][ni] = bq[qn][ni];

    bf16x8 a[4][2], b0[2][2], b1[2][2];

    for (int t = 0; t < NT; ++t) {
      char* Ab  = smem + (t & 1) * 65536;              // K(t)
      char* Bb  = Ab + 32768;
      char* Ab1 = smem + (((t + 1) & 1) * 65536);      // K(t+1) A13 dest
      const bool st1 = (t + 1 < NT) || (j + 1 < NTILES);
      const bool st2 = (t + 2 < NT) || (j + 1 < NTILES);
      const unsigned short* sA1 = (t + 1 < NT) ? gA + (size_t)(t + 1) * 64 : gAn;
      const unsigned short* sA2 = (t + 2 < NT) ? gA + (size_t)(t + 2) * 64
                                               : gAn + (size_t)(t + 2 - NT) * 64;
      const unsigned short* sB2 = (t + 2 < NT) ? gB + (size_t)(t + 2) * 64
                                               : gBn + (size_t)(t + 2 - NT) * 64;

      // ---- ph_A: read B(all)+A-lo; stage K(t+1).A{1,3}; MFMA qm=0 ----
      #pragma unroll
      for (int ni = 0; ni < 2; ++ni) {
        const char* p0 = Bb + bbase + ni * (16 * 128);
        b0[ni][0] = *(const bf16x8*)(p0 + sw0);
        b0[ni][1] = *(const bf16x8*)(p0 + sw1);
        const char* p1 = Bb + bbase + (32 + ni * 16) * 128;
        b1[ni][0] = *(const bf16x8*)(p1 + sw0);
        b1[ni][1] = *(const bf16x8*)(p1 + sw1);
      }
      #pragma unroll
      for (int mi = 0; mi < 4; ++mi) {
        const char* p = Ab + abase + mi * (16 * 128);
        a[mi][0] = *(const bf16x8*)(p + sw0);
        a[mi][1] = *(const bf16x8*)(p + sw1);
      }
      if (st1) STAGE_H2(sA1, Ab1, 1, 3);
      BAR;
      __builtin_amdgcn_s_setprio(1);
      #pragma unroll
      for (int mi = 0; mi < 4; ++mi)
        #pragma unroll
        for (int ni = 0; ni < 2; ++ni) {
          acc[0][0][mi][ni] = __builtin_amdgcn_mfma_f32_16x16x32_bf16(b0[ni][0], a[mi][0], acc[0][0][mi][ni], 0, 0, 0);
          acc[0][0][mi][ni] = __builtin_amdgcn_mfma_f32_16x16x32_bf16(b0[ni][1], a[mi][1], acc[0][0][mi][ni], 0, 0, 0);
          acc[0][1][mi][ni] = __builtin_amdgcn_mfma_f32_16x16x32_bf16(b1[ni][0], a[mi][0], acc[0][1][mi][ni], 0, 0, 0);
          acc[0][1][mi][ni] = __builtin_amdgcn_mfma_f32_16x16x32_bf16(b1[ni][1], a[mi][1], acc[0][1][mi][ni], 0, 0, 0);
        }
      __builtin_amdgcn_s_setprio(0);
      BAR;

      // ---- ph_B: read A-hi; stage K(t+2).B{0-3}+A{0,2}; MFMA qm=1 ----
      #pragma unroll
      for (int mi = 0; mi < 4; ++mi) {
        const char* p = Ab + abase + (64 + mi * 16) * 128;
        a[mi][0] = *(const bf16x8*)(p + sw0);
        a[mi][1] = *(const bf16x8*)(p + sw1);
      }
      if (st2) {
        STAGE_H2(sB2, Bb, 0, 1);
        STAGE_H2(sB2, Bb, 2, 3);
        STAGE_H2(sA2, Ab, 0, 2);
      }
      BAR;
      __builtin_amdgcn_s_setprio(1);
      #pragma unroll
      for (int mi = 0; mi < 4; ++mi)
        #pragma unroll
        for (int ni = 0; ni < 2; ++ni) {
          acc[1][0][mi][ni] = __builtin_amdgcn_mfma_f32_16x16x32_bf16(b0[ni][0], a[mi][0], acc[1][0][mi][ni], 0, 0, 0);
          acc[1][0][mi][ni] = __builtin_amdgcn_mfma_f32_16x16x32_bf16(b0[ni][1], a[mi][1], acc[1][0][mi][ni], 0, 0, 0);
          acc[1][1][mi][ni] = __builtin_amdgcn_mfma_f32_16x16x32_bf16(b1[ni][0], a[mi][0], acc[1][1][mi][ni], 0, 0, 0);
          acc[1][1][mi][ni] = __builtin_amdgcn_mfma_f32_16x16x32_bf16(b1[ni][1], a[mi][1], acc[1][1][mi][ni], 0, 0, 0);
        }
      __builtin_amdgcn_s_setprio(0);
      // queue: [t.phA(2)=K(t+1).A13, t.phB(6)=K(t+2)] -> vmcnt(6) = K(t+1)
      // complete (uniform, incl. t==0 where older stores retire too).
      if (st2) { asm volatile("s_waitcnt vmcnt(6)" ::: "memory"); }
      else     { asm volatile("s_waitcnt vmcnt(0)" ::: "memory"); }
      BAR;
    }

    // ---- epilogue: 32 pure f32x4 stores (bias already in acc) ----
    #pragma unroll
    for (int qm = 0; qm < 2; ++qm)
      #pragma unroll
      for (int mi = 0; mi < 4; ++mi) {
        const int m = m0 + wm * 128 + qm * 64 + mi * 16 + r15;
        const int bb_ = m >> 12, tt = m & 4095;
        float* orow = out + (size_t)bb_ * 8388608 + (size_t)tt * 128;
        #pragma unroll
        for (int qn = 0; qn < 2; ++qn)
          #pragma unroll
          for (int ni = 0; ni < 2; ++ni) {
            const int col = n0 + wn * 64 + qn * 32 + ni * 16 + q4 * 4;
            const int which = col >> 11, head = (col & 2047) >> 7, hd = col & 127;
            *reinterpret_cast<f32x4*>(orow + (size_t)which * 33554432 +
                                      (size_t)head * 524288 + hd) = acc[qm][qn][mi][ni];
          }
      }

    m0 = m0n; n0 = n0n; gA = gAn; gB = gBn;   // advance to next tile
  }
  #undef STAGE_T
  #undef STAGE_H2
  #undef TILE_MAP
}

// ---------- Fallback: naive fp32 ----------
__global__ __launch_bounds__(256) void naive_qkv(const float* __restrict__ h,
                                                 const float* __restrict__ w,
                                                 const float* __restrict__ bias,
                                                 float* __restrict__ out) {
  const int m = blockIdx.x;
  const int n = blockIdx.y * 256 + threadIdx.x;
  const float* hr = h + (size_t)m * K_DIM;
  float acc = bias[n];
  for (int k = 0; k < K_DIM; ++k) acc = fmaf(hr[k], w[(size_t)k * N_DIM + n], acc);
  const int which = n >> 11, head = (n & 2047) >> 7, hd = n & 127;
  const int bb = m >> 12, tt = m & 4095;
  out[(size_t)which * 33554432 + (size_t)bb * 8388608 + (size_t)head * 524288 +
      (size_t)tt * 128 + hd] = acc;
}

extern "C" void kernel_launch(void* const* d_in, const int* in_sizes, int n_in,
                              void* d_out, int out_size, void* d_ws, size_t ws_size,
                              hipStream_t stream) {
  const float* hidden = (const float*)d_in[0];
  const float* w_qkv  = (const float*)d_in[1];
  const float* b_qkv  = (const float*)d_in[2];
  float* out = (float*)d_out;

  const size_t needA = (size_t)M_DIM * K_DIM * 2;
  const size_t needB = (size_t)N_DIM * K_DIM * 2;
  if (ws_size >= needA + needB) {
    unsigned short* Abf = (unsigned short*)d_ws;
    unsigned short* Wt  = (unsigned short*)((char*)d_ws + needA);
    (void)hipFuncSetAttribute((const void*)gemm_qkv_8ph,
                              hipFuncAttributeMaxDynamicSharedMemorySize, 137216);
    cvt_fused<<<5120, 256, 0, stream>>>(hidden, Abf, w_qkv, Wt);
    gemm_qkv_8ph<<<256, 512, 137216, stream>>>(Abf, Wt, b_qkv, out);
  } else {
    naive_qkv<<<dim3(16384, 24), 256, 0, stream>>>(hidden, w_qkv, b_qkv, out);
  }
}